// Round 6
// baseline (67234.558 us; speedup 1.0000x reference)
//
#include <hip/hip_runtime.h>
#include <hip/hip_bf16.h>
#include <cstdint>
#include <cstddef>

// B=32, T=512, I=H=1024, L=2, gates 4H=4096. ALL buffers FP32 (per template:
// reference dtypes are float32). d_out fp32: outputs[32][512][1024] ++
// h_n[2][32][1024] ++ c_n[2][32][1024] = 16908288 floats.
// Correctness anchor: one kernel per (t,layer); gates = concat(x_t,h_prev)@W.T
// + b computed directly (concat-K=2048); fp32 state; ws = 768 KiB.

typedef unsigned short ush;

#define TT 512

__device__ __forceinline__ float sigm(float x) { return 1.f / (1.f + __expf(-x)); }

// ---------------------------------------------------------------------------
// One LSTM cell step for one layer.
// grid 512 = 128 c-groups (8 channels) x 4 b-quads (8 batches).
// 256 threads = kq16 (128 concat-k each) x bq4 (2 b each) x g4 (8 cols each).
// kq<8 -> x-part (k in [0,1024), from xbase rows); kq>=8 -> h-part
// (k in [1024,2048), from fp32 hs staged in LDS). W cols ARE concat-k.
// Consumer threads (tid<64) sum 16 partials + bias, activations, c/h update,
// optional fp32 output-row write.
// ---------------------------------------------------------------------------
__global__ __launch_bounds__(256) void lstm_cell(
    const float* __restrict__ xbase, long long xoff, long long xstride,
    const float* __restrict__ W, const float* __restrict__ bias,
    const float* __restrict__ hprev, float* __restrict__ hnew,
    float* __restrict__ oout, long long oout_stride,
    float* __restrict__ cst, int t) {
  __shared__ float hs[8][1028];          // 8 b-rows x 1024 fp32 (+4 pad)
  __shared__ float part[16][8][4][8];    // [kq][local b][gate][col]
  int tid = threadIdx.x;
  int c0i = (blockIdx.x & 127) * 8;
  int b0 = (blockIdx.x >> 7) * 8;
  int kq = tid >> 4;
  int bq = (tid >> 2) & 3;
  int g = tid & 3;
  int r0 = bq * 2, r1 = r0 + 1;

  if (t > 0) {  // stage h_prev rows b0..b0+7 into LDS
    int hr = tid >> 5, hseg = tid & 31;
    const float4* src = (const float4*)(hprev + (size_t)(b0 + hr) * 1024 + hseg * 32);
    float4* dst = (float4*)&hs[hr][hseg * 32];
#pragma unroll
    for (int i = 0; i < 8; ++i) dst[i] = src[i];
  }
  __syncthreads();

  float acc[2][8] = {{0.f}};
  bool hpart = (kq >= 8);
  if (!hpart || t > 0) {
    int kbase = kq * 128;
    const float* xr0 = nullptr;
    const float* xr1 = nullptr;
    if (!hpart) {
      xr0 = xbase + xoff + (long long)(b0 + r0) * xstride;
      xr1 = xbase + xoff + (long long)(b0 + r1) * xstride;
    }
    for (int k8 = 0; k8 < 16; ++k8) {
      int kc = kbase + k8 * 8;  // concat-k, 8 elements
      float a0[8], a1[8];
      if (hpart) {
        int kl = kc - 1024;
        float4 u0 = *(const float4*)&hs[r0][kl];
        float4 u1 = *(const float4*)&hs[r0][kl + 4];
        a0[0] = u0.x; a0[1] = u0.y; a0[2] = u0.z; a0[3] = u0.w;
        a0[4] = u1.x; a0[5] = u1.y; a0[6] = u1.z; a0[7] = u1.w;
        float4 v0 = *(const float4*)&hs[r1][kl];
        float4 v1 = *(const float4*)&hs[r1][kl + 4];
        a1[0] = v0.x; a1[1] = v0.y; a1[2] = v0.z; a1[3] = v0.w;
        a1[4] = v1.x; a1[5] = v1.y; a1[6] = v1.z; a1[7] = v1.w;
      } else {
        float4 u0 = *(const float4*)(xr0 + kc);
        float4 u1 = *(const float4*)(xr0 + kc + 4);
        a0[0] = u0.x; a0[1] = u0.y; a0[2] = u0.z; a0[3] = u0.w;
        a0[4] = u1.x; a0[5] = u1.y; a0[6] = u1.z; a0[7] = u1.w;
        float4 v0 = *(const float4*)(xr1 + kc);
        float4 v1 = *(const float4*)(xr1 + kc + 4);
        a1[0] = v0.x; a1[1] = v0.y; a1[2] = v0.z; a1[3] = v0.w;
        a1[4] = v1.x; a1[5] = v1.y; a1[6] = v1.z; a1[7] = v1.w;
      }
      // W rows g*1024 + c0i + j (j in [0,8)), col = concat-k
      const float* wp = W + (size_t)(g * 1024 + c0i) * 2048 + kc;
#pragma unroll
      for (int j = 0; j < 8; ++j) {
        const float* wr = wp + (size_t)j * 2048;
        float4 w0 = *(const float4*)wr;
        float4 w1 = *(const float4*)(wr + 4);
        float wf[8] = {w0.x, w0.y, w0.z, w0.w, w1.x, w1.y, w1.z, w1.w};
#pragma unroll
        for (int m = 0; m < 8; ++m) {
          acc[0][j] += a0[m] * wf[m];
          acc[1][j] += a1[m] * wf[m];
        }
      }
    }
  }
#pragma unroll
  for (int j = 0; j < 8; ++j) {
    part[kq][r0][g][j] = acc[0][j];
    part[kq][r1][g][j] = acc[1][j];
  }
  __syncthreads();

  if (tid < 64) {
    int bi = tid >> 3;
    int c = tid & 7;
    int b = b0 + bi;
    float gate[4];
#pragma unroll
    for (int ggi = 0; ggi < 4; ++ggi) {
      float s = bias[ggi * 1024 + c0i + c];
#pragma unroll
      for (int kk = 0; kk < 16; ++kk) s += part[kk][bi][ggi][c];
      gate[ggi] = s;
    }
    float fg = sigm(gate[0]);   // reference order: f, i, g, o
    float ig = sigm(gate[1]);
    float gg_ = tanhf(gate[2]);
    float og = sigm(gate[3]);
    size_t cidx = (size_t)b * 1024 + c0i + c;
    float cp = (t > 0) ? cst[cidx] : 0.f;
    float cn = fg * cp + ig * gg_;
    cst[cidx] = cn;
    float hn = og * tanhf(cn);
    hnew[cidx] = hn;
    if (oout) oout[(size_t)b * oout_stride + c0i + c] = hn;
  }
}

// ---------------------------------------------------------------------------
// Final h_n / c_n (fp32). 131072 threads.
// ---------------------------------------------------------------------------
__global__ __launch_bounds__(256) void finalize_k(const float* __restrict__ h0f,
                                                  const float* __restrict__ h1f,
                                                  const float* __restrict__ cbase,
                                                  float* __restrict__ dout) {
  int i = blockIdx.x * 256 + threadIdx.x;  // 0..131071
  size_t base = (size_t)32 * TT * 1024;    // 16777216
  float v;
  if (i < 32768) v = h0f[i];
  else if (i < 65536) v = h1f[i - 32768];
  else v = cbase[i - 65536];               // cbase = c[2][32][1024] contiguous
  dout[base + i] = v;
}

extern "C" void kernel_launch(void* const* d_in, const int* in_sizes, int n_in,
                              void* d_out, int out_size, void* d_ws, size_t ws_size,
                              hipStream_t stream) {
  const float* x = (const float*)d_in[0];
  const float* W0 = (const float*)d_in[1];
  const float* b0 = (const float*)d_in[2];
  const float* W1 = (const float*)d_in[3];
  const float* b1 = (const float*)d_in[4];
  float* OUT = (float*)d_out;

  // ws: h0[2][32][1024] ++ h1[2][32][1024] ++ c[2][32][1024], fp32 = 768 KiB.
  float* h0 = (float*)d_ws;
  float* h1 = h0 + 2 * 32768;
  float* c0 = h1 + 2 * 32768;
  float* c1 = c0 + 32768;

  for (int t = 0; t < TT; ++t) {
    int wr = t & 1;
    int rd = (t + 1) & 1;
    // layer 0: input row = x[b][t][*]  (offset t*1024, batch stride T*1024)
    lstm_cell<<<512, 256, 0, stream>>>(
        x, (long long)t * 1024, (long long)TT * 1024,
        W0, b0, h0 + (size_t)rd * 32768, h0 + (size_t)wr * 32768,
        (float*)nullptr, 0, c0, t);
    // layer 1: input = h0 slot just written (batch stride 1024); also writes
    // the outputs row OUT[b][t][*].
    lstm_cell<<<512, 256, 0, stream>>>(
        h0 + (size_t)wr * 32768, 0, 1024,
        W1, b1, h1 + (size_t)rd * 32768, h1 + (size_t)wr * 32768,
        OUT + (size_t)t * 1024, (long long)TT * 1024, c1, t);
  }

  // t=511 wrote slot 1
  finalize_k<<<512, 256, 0, stream>>>(h0 + 32768, h1 + 32768, c0, OUT);
}

// Round 7
// 14861.211 us; speedup vs baseline: 4.5242x; 4.5242x over previous
//
#include <hip/hip_runtime.h>
#include <hip/hip_bf16.h>
#include <cstdint>
#include <cstddef>

// B=32, T=512, I=H=1024, L=2, gates 4H=4096. fp32 in/out (verified R5).
// d_out fp32: outputs[32][512][1024] ++ h_n[2][32][1024] ++ c_n[2][32][1024].
// Structure: per chunk of Tc steps: G = x@Wx^T + b (bf16 MFMA GEMM, fp32 out)
// -> Tc recurrent MFMA steps (gates = G + h@Wh^T, fused pointwise)
// -> layer-1 GEMM on chunk's H0 -> Tc layer-1 steps writing fp32 OUT rows.
// Internal: W/h bf16 (threshold is 8*bf16 eps), c/G fp32.

typedef unsigned short ush;
typedef short bf16x8 __attribute__((ext_vector_type(8)));
typedef float f32x4 __attribute__((ext_vector_type(4)));

#define TT 512

__device__ __forceinline__ ush f2bf(float f) {
  __hip_bfloat16 h = __float2bfloat16(f);
  return *reinterpret_cast<ush*>(&h);
}
__device__ __forceinline__ float sigm(float x) { return 1.f / (1.f + __expf(-x)); }

// ---------------------------------------------------------------------------
// Whb[j][k] = bf16(W[j][1024+k]). grid 4096 (one row/block), 256 thr x 4 elems.
// ---------------------------------------------------------------------------
__global__ __launch_bounds__(256) void cast_wh(const float* __restrict__ W,
                                               ush* __restrict__ Whb) {
  int j = blockIdx.x;
  int k = threadIdx.x * 4;
  float4 v = *(const float4*)(W + (size_t)j * 2048 + 1024 + k);
  ushort4 o;
  o.x = f2bf(v.x); o.y = f2bf(v.y); o.z = f2bf(v.z); o.w = f2bf(v.w);
  *(ushort4*)(Whb + (size_t)j * 1024 + k) = o;
}

__global__ __launch_bounds__(256) void zero64k(uint4* __restrict__ p) {
  p[blockIdx.x * 256 + threadIdx.x] = uint4{0, 0, 0, 0};
}

// ---------------------------------------------------------------------------
// 128x128 MFMA GEMM: G[r][j] = bias[j] + sum_{k<1024} A[r][k]*W[j][k].
// mode 0: A row r=(lt*32+b) -> x[b][t0+lt][*] fp32 (cvt in staging).
// mode 1: A = H0c bf16, row r contiguous.
// B = W fp32 rows j, stride 2048, x-half cols [0,1024) (cvt in staging).
// 256 thr = 4 waves (2x2 of 64x64), BK=64, LDS stride 88 (16B-aligned, 2-way).
// grid(32, Tc*32/128).
// ---------------------------------------------------------------------------
__global__ __launch_bounds__(256) void gemm128(
    const float* __restrict__ xA, const ush* __restrict__ hA,
    const float* __restrict__ W, const float* __restrict__ bias,
    float* __restrict__ G, int mode, int t0) {
  __shared__ ush As[128][88];
  __shared__ ush Bs[128][88];
  int tid = threadIdx.x;
  int bn = blockIdx.x, bm = blockIdx.y;
  int srow = tid >> 1;                // staging row 0..127
  int shalf = (tid & 1) * 32;         // 32-elem half
  int lane = tid & 63, quad = lane >> 4, l15 = lane & 15;
  int w = tid >> 6;
  int m_base = (w >> 1) * 64, n_base = (w & 1) * 64;

  int r = bm * 128 + srow;
  const float* axf = nullptr;
  const ush* axh = nullptr;
  if (mode == 0)
    axf = xA + ((size_t)(r & 31) * TT + t0 + (r >> 5)) * 1024;
  else
    axh = hA + (size_t)r * 1024;
  const float* wrow = W + (size_t)(bn * 128 + srow) * 2048;

  f32x4 acc[4][4];
#pragma unroll
  for (int i = 0; i < 4; ++i)
#pragma unroll
    for (int j = 0; j < 4; ++j) acc[i][j] = f32x4{0.f, 0.f, 0.f, 0.f};

  for (int k0 = 0; k0 < 1024; k0 += 64) {
    // stage A (32 elems/thread)
    if (mode == 0) {
      const float* p = axf + k0 + shalf;
      ush* d = &As[srow][shalf];
#pragma unroll
      for (int s = 0; s < 8; ++s) {
        float4 v = ((const float4*)p)[s];
        ushort4 o;
        o.x = f2bf(v.x); o.y = f2bf(v.y); o.z = f2bf(v.z); o.w = f2bf(v.w);
        ((ushort4*)d)[s] = o;
      }
    } else {
      const uint4* p = (const uint4*)(axh + k0 + shalf);
      uint4* d = (uint4*)&As[srow][shalf];
#pragma unroll
      for (int s = 0; s < 4; ++s) d[s] = p[s];
    }
    // stage B (fp32 W -> bf16)
    {
      const float* p = wrow + k0 + shalf;
      ush* d = &Bs[srow][shalf];
#pragma unroll
      for (int s = 0; s < 8; ++s) {
        float4 v = ((const float4*)p)[s];
        ushort4 o;
        o.x = f2bf(v.x); o.y = f2bf(v.y); o.z = f2bf(v.z); o.w = f2bf(v.w);
        ((ushort4*)d)[s] = o;
      }
    }
    __syncthreads();
#pragma unroll
    for (int kc = 0; kc < 2; ++kc) {
      bf16x8 af[4], bf_[4];
#pragma unroll
      for (int i = 0; i < 4; ++i)
        af[i] = *(const bf16x8*)&As[m_base + i * 16 + l15][kc * 32 + quad * 8];
#pragma unroll
      for (int j = 0; j < 4; ++j)
        bf_[j] = *(const bf16x8*)&Bs[n_base + j * 16 + l15][kc * 32 + quad * 8];
#pragma unroll
      for (int i = 0; i < 4; ++i)
#pragma unroll
        for (int j = 0; j < 4; ++j)
          acc[i][j] = __builtin_amdgcn_mfma_f32_16x16x32_bf16(af[i], bf_[j],
                                                              acc[i][j], 0, 0, 0);
    }
    __syncthreads();
  }

  // epilogue: D row = m_base+i*16+quad*4+reg, col = n_base+j*16+l15
#pragma unroll
  for (int j = 0; j < 4; ++j) {
    int col = bn * 128 + n_base + j * 16 + l15;
    float bj = bias[col];
#pragma unroll
    for (int i = 0; i < 4; ++i) {
      int row = bm * 128 + m_base + i * 16 + quad * 4;
#pragma unroll
      for (int reg = 0; reg < 4; ++reg)
        G[(size_t)(row + reg) * 4096 + col] = acc[i][j][reg] + bj;
    }
  }
}

// ---------------------------------------------------------------------------
// One recurrent step (MFMA). gates[b][g*1024+c0+c] = G[lt*32+b][..] +
// (h_prev @ Wh^T)[..]; fused activations, c/h update.
// grid 64 (c-slices of 16), 512 thr = 8 waves: w = kh*4+g (K-half, gate).
// Per wave: 2 m-tiles (b 0..15, 16..31), K-half 512 = 16 chunks of 32.
// Partials combined in LDS; pointwise by 512 thr (b,c).
// ---------------------------------------------------------------------------
__global__ __launch_bounds__(512) void lstm_step(
    const float* __restrict__ G, int lt,
    const ush* __restrict__ Whb,
    const ush* __restrict__ hprev, ush* __restrict__ hnext,
    float* __restrict__ of32, long long of32_bstride,
    float* __restrict__ cst, float* __restrict__ hnf32, int t) {
  __shared__ float pg[8][32][16];  // [w=kh*4+g][b][c]
  int tid = threadIdx.x;
  int c0 = blockIdx.x * 16;
  int w = tid >> 6, lane = tid & 63, quad = lane >> 4, l15 = lane & 15;
  int g = w & 3, kh = w >> 2;

  f32x4 acc0 = {0.f, 0.f, 0.f, 0.f}, acc1 = {0.f, 0.f, 0.f, 0.f};
  const ush* bp = Whb + (size_t)(g * 1024 + c0 + l15) * 1024 + kh * 512 + quad * 8;
  const ush* ap0 = hprev + (size_t)l15 * 1024 + kh * 512 + quad * 8;
  const ush* ap1 = ap0 + 16 * 1024;
#pragma unroll
  for (int ch = 0; ch < 16; ++ch) {
    bf16x8 bv = *(const bf16x8*)(bp + ch * 32);
    bf16x8 a0 = *(const bf16x8*)(ap0 + ch * 32);
    bf16x8 a1 = *(const bf16x8*)(ap1 + ch * 32);
    acc0 = __builtin_amdgcn_mfma_f32_16x16x32_bf16(a0, bv, acc0, 0, 0, 0);
    acc1 = __builtin_amdgcn_mfma_f32_16x16x32_bf16(a1, bv, acc1, 0, 0, 0);
  }
#pragma unroll
  for (int reg = 0; reg < 4; ++reg) {
    pg[w][quad * 4 + reg][l15] = acc0[reg];
    pg[w][16 + quad * 4 + reg][l15] = acc1[reg];
  }
  __syncthreads();

  int b = tid >> 4, c = tid & 15;  // 512 = 32 x 16
  const float* grow = G + (size_t)(lt * 32 + b) * 4096 + c0 + c;
  float s0 = grow[0]    + pg[0][b][c] + pg[4][b][c];
  float s1 = grow[1024] + pg[1][b][c] + pg[5][b][c];
  float s2 = grow[2048] + pg[2][b][c] + pg[6][b][c];
  float s3 = grow[3072] + pg[3][b][c] + pg[7][b][c];
  float fg = sigm(s0), ig = sigm(s1), gv = tanhf(s2), og = sigm(s3);
  int ci = b * 1024 + c0 + c;
  float cp = (t > 0) ? cst[ci] : 0.f;
  float cn = fg * cp + ig * gv;
  cst[ci] = cn;
  float hn = og * tanhf(cn);
  hnext[ci] = f2bf(hn);
  if (of32) of32[(size_t)b * of32_bstride + c0 + c] = hn;
  if (hnf32) hnf32[ci] = hn;
}

// ---------------------------------------------------------------------------
// c_n copy (fp32 exact). 65536 elements.
// ---------------------------------------------------------------------------
__global__ __launch_bounds__(256) void fin_c(const float* __restrict__ cst,
                                             float* __restrict__ dst) {
  int i = blockIdx.x * 256 + threadIdx.x;
  dst[i] = cst[i];
}

extern "C" void kernel_launch(void* const* d_in, const int* in_sizes, int n_in,
                              void* d_out, int out_size, void* d_ws, size_t ws_size,
                              hipStream_t stream) {
  const float* x = (const float*)d_in[0];
  const float* W0 = (const float*)d_in[1];
  const float* b0 = (const float*)d_in[2];
  const float* W1 = (const float*)d_in[3];
  const float* b1 = (const float*)d_in[4];
  float* OUT = (float*)d_out;

  // ws layout (bytes):
  //   Whb0 [4096][1024] bf16 : 0        .. 8388608
  //   Whb1                    : 8388608 .. 16777216
  //   zbuf [32][1024] bf16    : 16777216 (64 KiB, zeroed)
  //   hs1a/hs1b bf16          : 16842752 / 16908288 (64 KiB each)
  //   cst [2][32][1024] fp32  : 16973824 (256 KiB)
  //   G   [Tc*32][4096] fp32  : 17235968
  //   H0c [Tc*32][1024] bf16  : after G
  int Tc = 4;
  {
    const int cand[5] = {64, 32, 16, 8, 4};
    for (int i = 0; i < 5; ++i) {
      size_t need = 17235968ull + (size_t)cand[i] * 32 * 4096 * 4 +
                    (size_t)cand[i] * 32 * 1024 * 2;
      if (need <= ws_size) { Tc = cand[i]; break; }
    }
  }
  char* ws = (char*)d_ws;
  ush* Whb0 = (ush*)ws;
  ush* Whb1 = (ush*)(ws + 8388608);
  ush* zbuf = (ush*)(ws + 16777216);
  ush* hs1a = (ush*)(ws + 16842752);
  ush* hs1b = (ush*)(ws + 16908288);
  float* cst0 = (float*)(ws + 16973824);
  float* cst1 = cst0 + 32768;
  float* G = (float*)(ws + 17235968);
  ush* H0c = (ush*)(ws + 17235968 + (size_t)Tc * 32 * 4096 * 4);

  cast_wh<<<4096, 256, 0, stream>>>(W0, Whb0);
  cast_wh<<<4096, 256, 0, stream>>>(W1, Whb1);
  zero64k<<<16, 256, 0, stream>>>((uint4*)zbuf);

  float* hn0 = OUT + 16777216;           // h_n layer 0
  float* hn1 = OUT + 16777216 + 32768;   // h_n layer 1
  dim3 ggrid(32, Tc / 4 * 1);            // N/128=32, M/128=Tc*32/128
  ggrid.y = (unsigned)(Tc * 32 / 128);

  const int NCH = TT / Tc;
  for (int ch = 0; ch < NCH; ++ch) {
    int t0 = ch * Tc;
    gemm128<<<ggrid, 256, 0, stream>>>(x, nullptr, W0, b0, G, 0, t0);
    for (int lt = 0; lt < Tc; ++lt) {
      int t = t0 + lt;
      const ush* hp = (t == 0) ? zbuf : H0c + (size_t)((lt + Tc - 1) % Tc) * 32768;
      ush* hx = H0c + (size_t)lt * 32768;
      lstm_step<<<64, 512, 0, stream>>>(G, lt, Whb0, hp, hx,
                                        (float*)nullptr, 0ll, cst0,
                                        (t == TT - 1) ? hn0 : (float*)nullptr, t);
    }
    gemm128<<<ggrid, 256, 0, stream>>>(nullptr, H0c, W1, b1, G, 1, t0);
    for (int lt = 0; lt < Tc; ++lt) {
      int t = t0 + lt;
      const ush* hp = (t == 0) ? zbuf : ((t & 1) ? hs1a : hs1b);
      ush* hx = (t & 1) ? hs1b : hs1a;
      lstm_step<<<64, 512, 0, stream>>>(G, lt, Whb1, hp, hx,
                                        OUT + (size_t)t * 1024, (long long)TT * 1024,
                                        cst1, (t == TT - 1) ? hn1 : (float*)nullptr, t);
    }
  }

  fin_c<<<256, 256, 0, stream>>>(cst0, OUT + 16777216 + 65536);
}